// Round 1
// baseline (79.713 us; speedup 1.0000x reference)
//
#include <hip/hip_runtime.h>

#define BINS 10
#define TPB  256

// Pass 1: per-bin {count, sum-of-BCE} over valid elements.
// Per-thread-private LDS slots -> no atomic contention; block tree-reduce;
// one global atomicAdd per bin per block.
__global__ __launch_bounds__(TPB) void ghmc_hist_kernel(
    const float4* __restrict__ pred4,
    const int4*   __restrict__ tgt4,
    const int4*   __restrict__ lw4,
    float* __restrict__ g_sums,
    int*   __restrict__ g_counts,
    int n4, int n)
{
    __shared__ float s_sum[BINS][TPB];
    __shared__ int   s_cnt[BINS][TPB];

    const int tid = threadIdx.x;
    #pragma unroll
    for (int b = 0; b < BINS; ++b) { s_sum[b][tid] = 0.f; s_cnt[b][tid] = 0; }
    // no sync needed: each thread only touches its own column until the reduce

    auto proc = [&](float p, int t, int w) {
        if (w > 0) {
            float ap  = fabsf(p);
            float e   = expf(-ap);                 // exp(-|p|)
            float inv = 1.f / (1.f + e);
            float sig = (p >= 0.f) ? inv : (e * inv);
            float tf  = (float)t;
            float g   = fabsf(sig - tf);
            int bin   = (int)(g * 10.f);
            bin = bin > (BINS - 1) ? (BINS - 1) : bin;
            // stable softplus(p) - t*p
            float bce = fmaxf(p, 0.f) + log1pf(e) - tf * p;
            s_sum[bin][tid] += bce;
            s_cnt[bin][tid] += 1;
        }
    };

    const int stride = gridDim.x * TPB;
    for (int i = blockIdx.x * TPB + tid; i < n4; i += stride) {
        float4 p = pred4[i];
        int4   t = tgt4[i];
        int4   w = lw4[i];
        proc(p.x, t.x, w.x);
        proc(p.y, t.y, w.y);
        proc(p.z, t.z, w.z);
        proc(p.w, t.w, w.w);
    }
    // scalar tail (N not divisible by 4)
    const float* predf = (const float*)pred4;
    const int*   tgtf  = (const int*)tgt4;
    const int*   lwf   = (const int*)lw4;
    for (int i = n4 * 4 + blockIdx.x * TPB + tid; i < n; i += stride) {
        proc(predf[i], tgtf[i], lwf[i]);
    }

    __syncthreads();
    for (int s = TPB / 2; s > 0; s >>= 1) {
        if (tid < s) {
            #pragma unroll
            for (int b = 0; b < BINS; ++b) {
                s_sum[b][tid] += s_sum[b][tid + s];
                s_cnt[b][tid] += s_cnt[b][tid + s];
            }
        }
        __syncthreads();
    }
    if (tid < BINS) {
        atomicAdd(&g_sums[tid],   s_sum[tid][0]);
        atomicAdd(&g_counts[tid], s_cnt[tid][0]);
    }
}

// Pass 2: tiny finalize — reproduce the reference arithmetic order.
__global__ void ghmc_final_kernel(const float* __restrict__ g_sums,
                                  const int*   __restrict__ g_counts,
                                  float* __restrict__ out)
{
    if (blockIdx.x == 0 && threadIdx.x == 0) {
        int ti = 0, nb = 0;
        #pragma unroll
        for (int b = 0; b < BINS; ++b) {
            ti += g_counts[b];
            nb += (g_counts[b] > 0) ? 1 : 0;
        }
        float total = fmaxf((float)ti, 1.f);
        float n     = (float)(nb > 0 ? nb : 1);
        float loss  = 0.f;
        #pragma unroll
        for (int b = 0; b < BINS; ++b) {
            if (g_counts[b] > 0) {
                float w = (total / (float)g_counts[b]) / n;   // w_bin[b]
                loss += w * g_sums[b];
            }
        }
        out[0] = loss / total * 1.0f;  // LOSS_WEIGHT = 1.0
    }
}

extern "C" void kernel_launch(void* const* d_in, const int* in_sizes, int n_in,
                              void* d_out, int out_size, void* d_ws, size_t ws_size,
                              hipStream_t stream)
{
    const float4* pred4 = (const float4*)d_in[0];
    const int4*   tgt4  = (const int4*)d_in[1];
    const int4*   lw4   = (const int4*)d_in[2];

    const int n  = in_sizes[0];
    const int n4 = n / 4;

    float* g_sums   = (float*)d_ws;
    int*   g_counts = (int*)((char*)d_ws + BINS * sizeof(float));

    // zero the 10 sums + 10 counts (async memset is graph-capturable)
    hipMemsetAsync(d_ws, 0, BINS * (sizeof(float) + sizeof(int)), stream);

    int blocks = (n4 + TPB - 1) / TPB;
    if (blocks > 2048) blocks = 2048;
    if (blocks < 1)    blocks = 1;

    ghmc_hist_kernel<<<blocks, TPB, 0, stream>>>(pred4, tgt4, lw4,
                                                 g_sums, g_counts, n4, n);
    ghmc_final_kernel<<<1, 64, 0, stream>>>(g_sums, g_counts, (float*)d_out);
}